// Round 1
// baseline (1831.121 us; speedup 1.0000x reference)
//
#include <hip/hip_runtime.h>

#define D_DIM 256
#define K_CODES 1024
#define T_DIM 4096
#define TN 64          // points (t values) per block
#define CK 16          // codes per chunk per thread
#define NGROUP 4       // wave-groups per block (256 threads / 64)
#define KPG (K_CODES / NGROUP)  // 256 codes per group

// --- prep: eN[k] = ||E[k]||^2 accumulated in fp64 ---
__global__ __launch_bounds__(256) void vq_norm_kernel(const float* __restrict__ E,
                                                      float* __restrict__ eN) {
    __shared__ double wsum[4];
    const int k = blockIdx.x;
    const int tid = threadIdx.x;
    float v = E[(size_t)k * D_DIM + tid];
    double s = (double)v * (double)v;
    #pragma unroll
    for (int off = 32; off > 0; off >>= 1)
        s += __shfl_down(s, off);
    if ((tid & 63) == 0) wsum[tid >> 6] = s;
    __syncthreads();
    if (tid == 0) {
        double tot = (wsum[0] + wsum[1]) + (wsum[2] + wsum[3]);
        eN[k] = (float)tot;
    }
}

// --- main: per-point argmin over codes + fused gather ---
__global__ __launch_bounds__(256, 2) void vq_main_kernel(const float* __restrict__ z,
                                                         const float* __restrict__ E,
                                                         const float* __restrict__ eN,
                                                         float* __restrict__ out) {
    __shared__ float z_lds[D_DIM][TN];   // 64 KiB, d-major: z_lds[d][point]

    const int tid = threadIdx.x;
    const int tt  = tid & 63;                                    // point / lane
    const int dg  = __builtin_amdgcn_readfirstlane(tid >> 6);    // wave group (uniform)
    const int b   = blockIdx.y;
    const int t0  = blockIdx.x * TN;

    // stage z[b][:, t0..t0+63] into LDS (coalesced 256B reads, stride-1 LDS writes)
    const float* zb = z + (size_t)b * D_DIM * T_DIM + t0;
    #pragma unroll 4
    for (int i = 0; i < TN; ++i) {
        int d = dg * 64 + i;
        z_lds[d][tt] = zb[(size_t)d * T_DIM + tt];
    }
    __syncthreads();

    const int p = tt;
    float bestd = __builtin_huge_valf();
    int bestk = 0;

    for (int chunk = 0; chunk < KPG / CK; ++chunk) {
        const int k0 = dg * KPG + chunk * CK;   // uniform -> scalar loads for E
        float acc0[CK], acc1[CK];
        #pragma unroll
        for (int c = 0; c < CK; ++c) { acc0[c] = 0.0f; acc1[c] = 0.0f; }

        const float* Eb = E + (size_t)k0 * D_DIM;
        #pragma unroll 2
        for (int d = 0; d < D_DIM; d += 4) {
            float z0 = z_lds[d + 0][p];
            float z1 = z_lds[d + 1][p];
            float z2 = z_lds[d + 2][p];
            float z3 = z_lds[d + 3][p];
            #pragma unroll
            for (int c = 0; c < CK; ++c) {
                const float* er = Eb + c * D_DIM + d;   // uniform address
                acc0[c] = fmaf(z0, er[0], acc0[c]);
                acc1[c] = fmaf(z1, er[1], acc1[c]);
                acc0[c] = fmaf(z2, er[2], acc0[c]);
                acc1[c] = fmaf(z3, er[3], acc1[c]);
            }
        }
        #pragma unroll
        for (int c = 0; c < CK; ++c) {
            float dist = eN[k0 + c] - 2.0f * (acc0[c] + acc1[c]);
            // strict < with ascending k == first-min tie-break (matches jnp.argmin)
            if (dist < bestd) { bestd = dist; bestk = k0 + c; }
        }
    }

    __syncthreads();   // everyone done reading z_lds; reuse it for the reduction
    float* rmin = &z_lds[0][0];          // 256 floats
    int*   ridx = (int*)&z_lds[8][0];    // 256 ints (disjoint region)
    rmin[dg * 64 + p] = bestd;
    ridx[dg * 64 + p] = bestk;
    __syncthreads();

    if (tid < TN) {
        float bd = rmin[tid];
        int   bk = ridx[tid];
        #pragma unroll
        for (int g2 = 1; g2 < NGROUP; ++g2) {   // ascending group order: keeps lowest k on ties
            float d2 = rmin[g2 * 64 + tid];
            int   k2 = ridx[g2 * 64 + tid];
            if (d2 < bd) { bd = d2; bk = k2; }
        }
        ridx[tid] = bk;
    }
    __syncthreads();

    // fused gather: out[b][d][t0+tt] = E[idx][d], coalesced along tt
    const int kidx = ridx[tt];
    const float* erow = E + (size_t)kidx * D_DIM;
    float* ob = out + (size_t)b * D_DIM * T_DIM + t0;
    #pragma unroll 4
    for (int i = 0; i < TN; ++i) {
        int d = dg * 64 + i;
        ob[(size_t)d * T_DIM + tt] = erow[d];
    }
}

extern "C" void kernel_launch(void* const* d_in, const int* in_sizes, int n_in,
                              void* d_out, int out_size, void* d_ws, size_t ws_size,
                              hipStream_t stream) {
    const float* z = (const float*)d_in[0];
    const float* E = (const float*)d_in[1];
    float* out = (float*)d_out;
    float* eN  = (float*)d_ws;   // 1024 floats

    const int B = in_sizes[0] / (D_DIM * T_DIM);   // 32

    vq_norm_kernel<<<dim3(K_CODES), dim3(256), 0, stream>>>(E, eN);

    dim3 grid(T_DIM / TN, B);
    vq_main_kernel<<<grid, dim3(256), 0, stream>>>(z, E, eN, out);
}

// Round 2
// 242.614 us; speedup vs baseline: 7.5475x; 7.5475x over previous
//
#include <hip/hip_runtime.h>

#define D_DIM 256
#define K_CODES 1024
#define T_DIM 4096
#define MTILE 128
#define NCHUNK 32
#define NCHUNKS (K_CODES / NCHUNK)          // 32
#define PART_BYTES (NCHUNK * D_DIM * 2)     // 16384 (one f16 part of a chunk)
#define CHUNK_BYTES (2 * PART_BYTES)        // 32768 (hi+lo)

typedef _Float16 f16x8 __attribute__((ext_vector_type(8)));
typedef float    f32x4 __attribute__((ext_vector_type(4)));

// ws layout: [0,4096): eN f32[1024]; [4096, 4096+1 MiB): swizzled E image (f16 hi/lo)

// --- prep 1: eN[k] = ||E[k]||^2 (fp64 accum) ---
__global__ __launch_bounds__(256) void vq_norm_kernel(const float* __restrict__ E,
                                                      float* __restrict__ eN) {
    __shared__ double wsum[4];
    const int k = blockIdx.x;
    const int tid = threadIdx.x;
    float v = E[(size_t)k * D_DIM + tid];
    double s = (double)v * (double)v;
    #pragma unroll
    for (int off = 32; off > 0; off >>= 1)
        s += __shfl_down(s, off);
    if ((tid & 63) == 0) wsum[tid >> 6] = s;
    __syncthreads();
    if (tid == 0) eN[k] = (float)((wsum[0] + wsum[1]) + (wsum[2] + wsum[3]));
}

// --- prep 2: E -> f16 hi/lo, stored as the pre-swizzled LDS chunk image ---
__global__ __launch_bounds__(256) void vq_prep_e(const float* __restrict__ E,
                                                 char* __restrict__ img) {
    const int g  = blockIdx.x * 256 + threadIdx.x;   // 0..32767
    const int k  = g >> 5;                           // code 0..1023
    const int dg = g & 31;                           // d-group of 8
    const float* src = E + (size_t)k * D_DIM + dg * 8;
    f16x8 hi, lo;
    #pragma unroll
    for (int j = 0; j < 8; ++j) {
        float v = src[j];
        _Float16 h = (_Float16)v;
        hi[j] = h;
        lo[j] = (_Float16)(v - (float)h);
    }
    const int chunk = k >> 5, code = k & 31;
    size_t off = (size_t)chunk * CHUNK_BYTES + code * 512 + ((dg * 16) ^ ((code & 7) << 4));
    *(f16x8*)(img + off) = hi;
    *(f16x8*)(img + off + PART_BYTES) = lo;
}

__device__ __forceinline__ void stage_chunk(const char* gsrc, char* ldsdst, int tid) {
    const int lane = tid & 63;
    const int woff = (tid >> 6) << 10;   // wave*1024
    #pragma unroll
    for (int r = 0; r < 8; ++r) {
        __builtin_amdgcn_global_load_lds(
            (const __attribute__((address_space(1))) void*)(gsrc + r * 4096 + woff + (size_t)lane * 16),
            (__attribute__((address_space(3))) void*)(ldsdst + r * 4096 + woff),
            16, 0, 0);
    }
}

__global__ __launch_bounds__(256, 2) void vq_mfma_kernel(const float* __restrict__ z,
                                                         const float* __restrict__ E,
                                                         const float* __restrict__ eN_g,
                                                         const char* __restrict__ imgE,
                                                         float* __restrict__ out) {
    __shared__ __align__(16) char lds_all[2 * CHUNK_BYTES + 4096 + 512];
    char*  lds_e = lds_all;
    float* eN_s  = (float*)(lds_all + 2 * CHUNK_BYTES);
    int*   idx_s = (int*)(lds_all + 2 * CHUNK_BYTES + 4096);

    const int tid  = threadIdx.x;
    const int lane = tid & 63;
    const int w    = tid >> 6;        // wave 0..3
    const int l15  = lane & 15;
    const int kg   = lane >> 4;       // 0..3
    const int bb   = blockIdx.y;
    const int t0   = blockIdx.x * MTILE;

    // ---- A fragments: z loaded straight from global (coalesced), f16 hi/lo split
    const float* zb = z + (size_t)bb * D_DIM * T_DIM + t0;
    f16x8 a_hi[2][8], a_lo[2][8];
    #pragma unroll
    for (int s = 0; s < 2; ++s) {
        const int tcol = w * 32 + s * 16 + l15;
        #pragma unroll
        for (int ks = 0; ks < 8; ++ks) {
            #pragma unroll
            for (int j = 0; j < 8; ++j) {
                float v = zb[(size_t)(ks * 32 + kg * 8 + j) * T_DIM + tcol];
                _Float16 h = (_Float16)v;
                a_hi[s][ks][j] = h;
                a_lo[s][ks][j] = (_Float16)(v - (float)h);
            }
        }
    }

    // ---- stage eN + first E chunk
    for (int i = tid; i < K_CODES; i += 256) eN_s[i] = eN_g[i];
    stage_chunk(imgE, lds_e, tid);
    __syncthreads();

    float best[2][4];
    int   bestk[2][4];
    #pragma unroll
    for (int s = 0; s < 2; ++s)
        #pragma unroll
        for (int r = 0; r < 4; ++r) { best[s][r] = __builtin_huge_valf(); bestk[s][r] = 0; }

    for (int c = 0; c < NCHUNKS; ++c) {
        const char* ebuf = lds_e + (c & 1) * CHUNK_BYTES;
        if (c + 1 < NCHUNKS)
            stage_chunk(imgE + (size_t)(c + 1) * CHUNK_BYTES,
                        lds_e + ((c + 1) & 1) * CHUNK_BYTES, tid);

        #pragma unroll
        for (int nt = 0; nt < 2; ++nt) {
            const int  cl    = nt * 16 + l15;
            const int  swz   = (cl & 7) << 4;
            const char* bbase = ebuf + cl * 512;

            f32x4 aA0[2], aA1[2], aB[2], aC[2];
            #pragma unroll
            for (int s = 0; s < 2; ++s) {
                aA0[s] = (f32x4){0.f, 0.f, 0.f, 0.f};
                aA1[s] = (f32x4){0.f, 0.f, 0.f, 0.f};
                aB[s]  = (f32x4){0.f, 0.f, 0.f, 0.f};
                aC[s]  = (f32x4){0.f, 0.f, 0.f, 0.f};
            }

            #pragma unroll
            for (int ks = 0; ks < 8; ++ks) {
                const int ko = (ks * 64 + kg * 16) ^ swz;
                f16x8 bh = *(const f16x8*)(bbase + ko);
                f16x8 bl = *(const f16x8*)(bbase + ko + PART_BYTES);
                #pragma unroll
                for (int s = 0; s < 2; ++s) {
                    if (ks < 4)
                        aA0[s] = __builtin_amdgcn_mfma_f32_16x16x32_f16(a_hi[s][ks], bh, aA0[s], 0, 0, 0);
                    else
                        aA1[s] = __builtin_amdgcn_mfma_f32_16x16x32_f16(a_hi[s][ks], bh, aA1[s], 0, 0, 0);
                }
                #pragma unroll
                for (int s = 0; s < 2; ++s)
                    aB[s] = __builtin_amdgcn_mfma_f32_16x16x32_f16(a_hi[s][ks], bl, aB[s], 0, 0, 0);
                #pragma unroll
                for (int s = 0; s < 2; ++s)
                    aC[s] = __builtin_amdgcn_mfma_f32_16x16x32_f16(a_lo[s][ks], bh, aC[s], 0, 0, 0);
                #pragma unroll
                for (int s = 0; s < 2; ++s)
                    aB[s] = __builtin_amdgcn_mfma_f32_16x16x32_f16(a_lo[s][ks], bl, aB[s], 0, 0, 0);
            }

            const int n = c * NCHUNK + cl;
            const float en = eN_s[n];
            #pragma unroll
            for (int s = 0; s < 2; ++s) {
                f32x4 dsum = (aA0[s] + aA1[s]) + (aB[s] + aC[s]);
                #pragma unroll
                for (int r = 0; r < 4; ++r) {
                    float dist = en - 2.0f * dsum[r];
                    if (dist < best[s][r]) { best[s][r] = dist; bestk[s][r] = n; }
                }
            }
        }
        __syncthreads();   // drains stage vmcnt + lds reads before buffer swap
    }

    // ---- cross-lane argmin reduce over the 16 columns (bits 0-3 of lane)
    #pragma unroll
    for (int off = 1; off < 16; off <<= 1) {
        #pragma unroll
        for (int s = 0; s < 2; ++s) {
            #pragma unroll
            for (int r = 0; r < 4; ++r) {
                float od = __shfl_xor(best[s][r], off, 64);
                int   ok = __shfl_xor(bestk[s][r], off, 64);
                if (od < best[s][r] || (od == best[s][r] && ok < bestk[s][r])) {
                    best[s][r] = od; bestk[s][r] = ok;
                }
            }
        }
    }
    if (l15 == 0) {
        #pragma unroll
        for (int s = 0; s < 2; ++s)
            #pragma unroll
            for (int r = 0; r < 4; ++r)
                idx_s[w * 32 + s * 16 + kg * 4 + r] = bestk[s][r];
    }
    __syncthreads();

    // ---- fused gather: out[b][d][t0+p] = E[idx[p]][d]
    const int p  = tid & 127;
    const int dh = tid >> 7;
    const int kk = idx_s[p];
    const float* er = E + (size_t)kk * D_DIM + dh * 128;
    float* ob = out + (size_t)bb * D_DIM * T_DIM + t0 + p;
    #pragma unroll 8
    for (int i = 0; i < 128; ++i)
        ob[(size_t)(dh * 128 + i) * T_DIM] = er[i];
}

extern "C" void kernel_launch(void* const* d_in, const int* in_sizes, int n_in,
                              void* d_out, int out_size, void* d_ws, size_t ws_size,
                              hipStream_t stream) {
    const float* z = (const float*)d_in[0];
    const float* E = (const float*)d_in[1];
    float* out = (float*)d_out;
    float* eN  = (float*)d_ws;
    char*  img = (char*)d_ws + 4096;

    const int B = in_sizes[0] / (D_DIM * T_DIM);   // 32

    vq_norm_kernel<<<dim3(K_CODES), dim3(256), 0, stream>>>(E, eN);
    vq_prep_e<<<dim3((K_CODES * NCHUNK) / 256), dim3(256), 0, stream>>>(E, img);

    dim3 grid(T_DIM / MTILE, B);
    vq_mfma_kernel<<<grid, dim3(256), 0, stream>>>(z, E, eN, img, out);
}

// Round 3
// 208.115 us; speedup vs baseline: 8.7986x; 1.1658x over previous
//
#include <hip/hip_runtime.h>

#define D_DIM 256
#define K_CODES 1024
#define T_DIM 4096
#define MTILE 128
#define NCHUNK 32
#define NCHUNKS (K_CODES / NCHUNK)          // 32
#define PART_BYTES (NCHUNK * D_DIM * 2)     // 16384 (one f16 part of a chunk)
#define CHUNK_BYTES (2 * PART_BYTES)        // 32768 (hi+lo)

typedef _Float16 f16x8 __attribute__((ext_vector_type(8)));
typedef float    f32x4 __attribute__((ext_vector_type(4)));

// ws layout: [0,4096): eN f32[1024]; [4096, 4096+1 MiB): swizzled E image (f16 hi/lo)

// --- prep 1: eN[k] = ||E[k]||^2 (fp64 accum) ---
__global__ __launch_bounds__(256) void vq_norm_kernel(const float* __restrict__ E,
                                                      float* __restrict__ eN) {
    __shared__ double wsum[4];
    const int k = blockIdx.x;
    const int tid = threadIdx.x;
    float v = E[(size_t)k * D_DIM + tid];
    double s = (double)v * (double)v;
    #pragma unroll
    for (int off = 32; off > 0; off >>= 1)
        s += __shfl_down(s, off);
    if ((tid & 63) == 0) wsum[tid >> 6] = s;
    __syncthreads();
    if (tid == 0) eN[k] = (float)((wsum[0] + wsum[1]) + (wsum[2] + wsum[3]));
}

// --- prep 2: E -> f16 hi/lo, stored as the pre-swizzled LDS chunk image ---
__global__ __launch_bounds__(256) void vq_prep_e(const float* __restrict__ E,
                                                 char* __restrict__ img) {
    const int g  = blockIdx.x * 256 + threadIdx.x;   // 0..32767
    const int k  = g >> 5;                           // code 0..1023
    const int dg = g & 31;                           // d-group of 8
    const float* src = E + (size_t)k * D_DIM + dg * 8;
    f16x8 hi, lo;
    #pragma unroll
    for (int j = 0; j < 8; ++j) {
        float v = src[j];
        _Float16 h = (_Float16)v;
        hi[j] = h;
        lo[j] = (_Float16)(v - (float)h);
    }
    const int chunk = k >> 5, code = k & 31;
    size_t off = (size_t)chunk * CHUNK_BYTES + code * 512 + ((dg * 16) ^ ((code & 7) << 4));
    *(f16x8*)(img + off) = hi;
    *(f16x8*)(img + off + PART_BYTES) = lo;
}

__device__ __forceinline__ void stage_chunk(const char* gsrc, char* ldsdst, int tid) {
    const int lane = tid & 63;
    const int woff = (tid >> 6) << 10;   // wave*1024
    #pragma unroll
    for (int r = 0; r < 8; ++r) {
        __builtin_amdgcn_global_load_lds(
            (const __attribute__((address_space(1))) void*)(gsrc + r * 4096 + woff + (size_t)lane * 16),
            (__attribute__((address_space(3))) void*)(ldsdst + r * 4096 + woff),
            16, 0, 0);
    }
}

__global__ __launch_bounds__(256, 2) void vq_mfma_kernel(const float* __restrict__ z,
                                                         const float* __restrict__ E,
                                                         const float* __restrict__ eN_g,
                                                         const char* __restrict__ imgE,
                                                         float* __restrict__ out) {
    __shared__ __align__(16) char lds_all[2 * CHUNK_BYTES + 4096 + 512];
    char*  lds_e = lds_all;
    float* eN_s  = (float*)(lds_all + 2 * CHUNK_BYTES);
    int*   idx_s = (int*)(lds_all + 2 * CHUNK_BYTES + 4096);

    const int tid  = threadIdx.x;
    const int lane = tid & 63;
    const int w    = tid >> 6;        // wave 0..3
    const int l15  = lane & 15;
    const int kg   = lane >> 4;       // 0..3
    const int bb   = blockIdx.y;
    const int t0   = blockIdx.x * MTILE;

    // ---- A fragments: z loaded straight from global (coalesced), f16 hi/lo split
    const float* zb = z + (size_t)bb * D_DIM * T_DIM + t0;
    f16x8 a_hi[2][8], a_lo[2][8];
    #pragma unroll
    for (int s = 0; s < 2; ++s) {
        const int tcol = w * 32 + s * 16 + l15;
        #pragma unroll
        for (int ks = 0; ks < 8; ++ks) {
            #pragma unroll
            for (int j = 0; j < 8; ++j) {
                float v = zb[(size_t)(ks * 32 + kg * 8 + j) * T_DIM + tcol];
                _Float16 h = (_Float16)v;
                a_hi[s][ks][j] = h;
                a_lo[s][ks][j] = (_Float16)(v - (float)h);
            }
        }
    }

    // ---- stage eN + first E chunk
    for (int i = tid; i < K_CODES; i += 256) eN_s[i] = eN_g[i];
    stage_chunk(imgE, lds_e, tid);
    __syncthreads();

    float best[2][4];
    int   bestk[2][4];
    #pragma unroll
    for (int s = 0; s < 2; ++s)
        #pragma unroll
        for (int r = 0; r < 4; ++r) { best[s][r] = __builtin_huge_valf(); bestk[s][r] = 0; }

    for (int c = 0; c < NCHUNKS; ++c) {
        const char* ebuf = lds_e + (c & 1) * CHUNK_BYTES;
        if (c + 1 < NCHUNKS)
            stage_chunk(imgE + (size_t)(c + 1) * CHUNK_BYTES,
                        lds_e + ((c + 1) & 1) * CHUNK_BYTES, tid);

        #pragma unroll
        for (int nt = 0; nt < 2; ++nt) {
            const int  cl    = nt * 16 + l15;
            const int  swz   = (cl & 7) << 4;
            const char* bbase = ebuf + cl * 512;

            // per-lane code norm, loaded BEFORE the MFMA cluster (latency hidden)
            const float en = eN_s[c * NCHUNK + cl];

            // 6 independent accumulator chains: [strip][pass]
            f32x4 aH[2], aM[2], aL[2];
            #pragma unroll
            for (int s = 0; s < 2; ++s) {
                aH[s] = (f32x4){0.f, 0.f, 0.f, 0.f};
                aM[s] = (f32x4){0.f, 0.f, 0.f, 0.f};
                aL[s] = (f32x4){0.f, 0.f, 0.f, 0.f};
            }

            __builtin_amdgcn_s_setprio(1);
            #pragma unroll
            for (int ks = 0; ks < 8; ++ks) {
                const int ko = (ks * 64 + kg * 16) ^ swz;
                f16x8 bh = *(const f16x8*)(bbase + ko);
                f16x8 bl = *(const f16x8*)(bbase + ko + PART_BYTES);
                #pragma unroll
                for (int s = 0; s < 2; ++s)
                    aH[s] = __builtin_amdgcn_mfma_f32_16x16x32_f16(a_hi[s][ks], bh, aH[s], 0, 0, 0);
                #pragma unroll
                for (int s = 0; s < 2; ++s)
                    aM[s] = __builtin_amdgcn_mfma_f32_16x16x32_f16(a_hi[s][ks], bl, aM[s], 0, 0, 0);
                #pragma unroll
                for (int s = 0; s < 2; ++s)
                    aL[s] = __builtin_amdgcn_mfma_f32_16x16x32_f16(a_lo[s][ks], bh, aL[s], 0, 0, 0);
            }
            __builtin_amdgcn_s_setprio(0);

            const int n = c * NCHUNK + cl;
            #pragma unroll
            for (int s = 0; s < 2; ++s) {
                f32x4 dsum = (aH[s] + aM[s]) + aL[s];
                #pragma unroll
                for (int r = 0; r < 4; ++r) {
                    float dist = fmaf(-2.0f, dsum[r], en);
                    // strict < with ascending n == first-min tie-break (matches jnp.argmin)
                    if (dist < best[s][r]) { best[s][r] = dist; bestk[s][r] = n; }
                }
            }
        }
        __syncthreads();   // all waves done reading ebuf before it is restaged
    }

    // ---- cross-lane argmin reduce over the 16 columns (bits 0-3 of lane)
    #pragma unroll
    for (int off = 1; off < 16; off <<= 1) {
        #pragma unroll
        for (int s = 0; s < 2; ++s) {
            #pragma unroll
            for (int r = 0; r < 4; ++r) {
                float od = __shfl_xor(best[s][r], off, 64);
                int   ok = __shfl_xor(bestk[s][r], off, 64);
                if (od < best[s][r] || (od == best[s][r] && ok < bestk[s][r])) {
                    best[s][r] = od; bestk[s][r] = ok;
                }
            }
        }
    }
    if (l15 == 0) {
        #pragma unroll
        for (int s = 0; s < 2; ++s)
            #pragma unroll
            for (int r = 0; r < 4; ++r)
                idx_s[w * 32 + s * 16 + kg * 4 + r] = bestk[s][r];
    }
    __syncthreads();

    // ---- fused gather: out[b][d][t0+p] = E[idx[p]][d]
    const int p  = tid & 127;
    const int dh = tid >> 7;
    const int kk = idx_s[p];
    const float* er = E + (size_t)kk * D_DIM + dh * 128;
    float* ob = out + (size_t)bb * D_DIM * T_DIM + t0 + p;
    #pragma unroll 8
    for (int i = 0; i < 128; ++i)
        ob[(size_t)(dh * 128 + i) * T_DIM] = er[i];
}

extern "C" void kernel_launch(void* const* d_in, const int* in_sizes, int n_in,
                              void* d_out, int out_size, void* d_ws, size_t ws_size,
                              hipStream_t stream) {
    const float* z = (const float*)d_in[0];
    const float* E = (const float*)d_in[1];
    float* out = (float*)d_out;
    float* eN  = (float*)d_ws;
    char*  img = (char*)d_ws + 4096;

    const int B = in_sizes[0] / (D_DIM * T_DIM);   // 32

    vq_norm_kernel<<<dim3(K_CODES), dim3(256), 0, stream>>>(E, eN);
    vq_prep_e<<<dim3((K_CODES * NCHUNK) / 256), dim3(256), 0, stream>>>(E, img);

    dim3 grid(T_DIM / MTILE, B);
    vq_mfma_kernel<<<grid, dim3(256), 0, stream>>>(z, E, eN, img, out);
}